// Round 1
// baseline (2787.025 us; speedup 1.0000x reference)
//
#include <hip/hip_runtime.h>

#define NN 50000
#define EE 400000
#define HH 512
#define LL 4
#define OUTC 250
#define MP 50048               // NN padded to multiple of 128
#define HH2 (HH*HH)
#define INV_SQRT_H 0.044194173824159216f

typedef unsigned short u16;
typedef __attribute__((ext_vector_type(8))) unsigned short u16x8;
typedef __attribute__((ext_vector_type(8))) short s16x8;
typedef __attribute__((ext_vector_type(4))) float f32x4;

__device__ __forceinline__ float b2f(u16 v) {
  union { unsigned u; float f; } c; c.u = ((unsigned)v) << 16; return c.f;
}
__device__ __forceinline__ u16 f2b(float f) {
  union { float f; unsigned u; } c; c.f = f;
  unsigned r = c.u + 0x7fffu + ((c.u >> 16) & 1u);
  return (u16)(r >> 16);
}
__device__ __forceinline__ float leakyf(float v) { return v > 0.f ? v : 0.2f * v; }

__device__ __forceinline__ void async16(const void* g, void* l) {
  __builtin_amdgcn_global_load_lds((const __attribute__((address_space(1))) void*)g,
                                   (__attribute__((address_space(3))) void*)l,
                                   16, 0, 0);
}

// ---------------- CSR build ----------------
__global__ void k_hist(const int* __restrict__ dst, int* __restrict__ cnt) {
  int i = blockIdx.x * 256 + threadIdx.x;
  if (i < EE) atomicAdd(&cnt[dst[i]], 1);
}

__global__ void k_scan(const int* __restrict__ cnt, int* __restrict__ offs,
                       int* __restrict__ cursor, int n) {
  __shared__ int sm[1024];
  __shared__ int carrysh;
  int t = threadIdx.x;
  if (t == 0) carrysh = 0;
  __syncthreads();
  for (int base = 0; base < n; base += 1024) {
    int v = (base + t < n) ? cnt[base + t] : 0;
    sm[t] = v;
    __syncthreads();
#pragma unroll
    for (int d = 1; d < 1024; d <<= 1) {
      int u = (t >= d) ? sm[t - d] : 0;
      __syncthreads();
      sm[t] += u;
      __syncthreads();
    }
    int incl = sm[t];
    int carry = carrysh;
    if (base + t < n) { int ex = carry + incl - v; offs[base + t] = ex; cursor[base + t] = ex; }
    __syncthreads();
    if (t == 1023) carrysh = carry + incl;
    __syncthreads();
  }
  if (t == 0) offs[n] = carrysh;
}

__global__ void k_fill(const int* __restrict__ src, const int* __restrict__ dst,
                       const float2* __restrict__ pos, int* __restrict__ cursor,
                       int* __restrict__ csr, float* __restrict__ P) {
  int i = blockIdx.x * 256 + threadIdx.x;
  if (i >= EE) return;
  int s = src[i], d = dst[i];
  int slot = atomicAdd(&cursor[d], 1);
  csr[slot] = s;
  float2 a = pos[s], b = pos[d];
  atomicAdd(&P[2 * d], a.x - b.x);
  atomicAdd(&P[2 * d + 1], a.y - b.y);
}

__global__ void k_invc(const int* __restrict__ offs, float* __restrict__ invc) {
  int i = blockIdx.x * 256 + threadIdx.x;
  if (i >= NN) return;
  int c = offs[i + 1] - offs[i];
  invc[i] = 1.f / (float)(c > 1 ? c : 1);
}

// ---------------- weight prep (f32 -> bf16, transposed to [n][k]) ----------------
__global__ void k_transpose_many(const float* __restrict__ W, u16* __restrict__ WT, int nmat) {
  long idx = (long)blockIdx.x * 256 + threadIdx.x;
  if (idx >= (long)nmat * HH2) return;
  int m = (int)(idx / HH2);
  int rem = (int)(idx - (long)m * HH2);
  int r = rem % HH, c = rem / HH;
  WT[(size_t)m * HH2 + (size_t)c * HH + r] = f2b(W[(size_t)m * HH2 + (size_t)r * HH + c]);
}

__global__ void k_sum3_all(const float* __restrict__ Wr, u16* __restrict__ WT) {
  long idx = (long)blockIdx.x * 256 + threadIdx.x;
  if (idx >= 4L * HH2) return;
  int l = (int)(idx / HH2);
  int rem = (int)(idx - (long)l * HH2);
  int r = rem % HH, c = rem / HH;
  const float* W3 = Wr + (size_t)l * 3 * HH2;
  float v = W3[(size_t)r * HH + c] + W3[(size_t)HH2 + (size_t)r * HH + c] +
            W3[(size_t)2 * HH2 + (size_t)r * HH + c];
  WT[(size_t)l * HH2 + (size_t)c * HH + r] = f2b(v);
}

__global__ void k_transpose_pad(const float* __restrict__ W, u16* __restrict__ WT,
                                int rows, int cols, int tcols) {
  int idx = blockIdx.x * 256 + threadIdx.x;
  if (idx >= rows * tcols) return;
  int r = idx % rows, c = idx / rows;
  float v = (c < cols) ? W[(size_t)r * cols + c] : 0.f;
  WT[(size_t)c * rows + r] = f2b(v);
}

// ---------------- misc ----------------
__global__ void k_cvt(const float* __restrict__ in, u16* __restrict__ out, int n8) {
  int i = blockIdx.x * 256 + threadIdx.x;
  if (i >= n8) return;
  const float4 a = *(const float4*)(in + (size_t)i * 8);
  const float4 b = *(const float4*)(in + (size_t)i * 8 + 4);
  u16x8 o;
  o[0] = f2b(a.x); o[1] = f2b(a.y); o[2] = f2b(a.z); o[3] = f2b(a.w);
  o[4] = f2b(b.x); o[5] = f2b(b.y); o[6] = f2b(b.z); o[7] = f2b(b.w);
  *(u16x8*)(out + (size_t)i * 8) = o;
}

__global__ void k_zero_pads(u16* a, u16* b, u16* c, u16* d, u16* e) {
  int i = blockIdx.x * 256 + threadIdx.x;
  const int per = (MP - NN) * HH;
  if (i >= per * 5) return;
  int sel = i / per, rem = i - sel * per;
  u16* p = sel == 0 ? a : sel == 1 ? b : sel == 2 ? c : sel == 3 ? d : e;
  p[(size_t)NN * HH + rem] = 0;
}

// ---------------- pooling ----------------
__global__ void k_kvec(const float* __restrict__ Wk, const float* __restrict__ seed,
                       float* __restrict__ kvec) {
  int w = threadIdx.x >> 6, lane = threadIdx.x & 63;
  float sv[8];
#pragma unroll
  for (int i = 0; i < 8; ++i) sv[i] = seed[lane * 8 + i];
  for (int row = w; row < HH; row += 8) {
    const float* p = Wk + (size_t)row * HH + lane * 8;
    float d = 0.f;
#pragma unroll
    for (int i = 0; i < 8; ++i) d += p[i] * sv[i];
#pragma unroll
    for (int o = 32; o > 0; o >>= 1) d += __shfl_xor(d, o);
    if (lane == 0) kvec[row] = d;
  }
}

__global__ void k_scores(const u16* __restrict__ x, const float* __restrict__ kvec,
                         float* __restrict__ s, float* __restrict__ partials) {
  int wv = (blockIdx.x * blockDim.x + threadIdx.x) >> 6;
  int lane = threadIdx.x & 63;
  int nw = (gridDim.x * blockDim.x) >> 6;
  float kl[8];
#pragma unroll
  for (int i = 0; i < 8; ++i) kl[i] = kvec[lane * 8 + i];
  float lmax = -1e30f;
  for (int n = wv; n < NN; n += nw) {
    u16x8 v = *(const u16x8*)(x + (size_t)n * HH + lane * 8);
    float d = 0.f;
#pragma unroll
    for (int i = 0; i < 8; ++i) d += b2f(v[i]) * kl[i];
#pragma unroll
    for (int o = 32; o > 0; o >>= 1) d += __shfl_xor(d, o);
    d *= INV_SQRT_H;
    if (lane == 0) s[n] = d;
    lmax = fmaxf(lmax, d);
  }
  __shared__ float sm4[4];
  if (lane == 0) sm4[threadIdx.x >> 6] = lmax;
  __syncthreads();
  if (threadIdx.x == 0)
    partials[blockIdx.x] = fmaxf(fmaxf(sm4[0], sm4[1]), fmaxf(sm4[2], sm4[3]));
}

__global__ void k_maxr(const float* __restrict__ partials, float* __restrict__ m) {
  int t = threadIdx.x;
  float v = partials[t];
#pragma unroll
  for (int o = 32; o > 0; o >>= 1) v = fmaxf(v, __shfl_xor(v, o));
  __shared__ float sm[8];
  if ((t & 63) == 0) sm[t >> 6] = v;
  __syncthreads();
  if (t == 0) {
    float r = sm[0];
#pragma unroll
    for (int i = 1; i < 8; ++i) r = fmaxf(r, sm[i]);
    *m = r;
  }
}

__global__ void k_wsum(const u16* __restrict__ x, const float* __restrict__ s,
                       const float* __restrict__ mp, float* __restrict__ wx,
                       float* __restrict__ Zp) {
  int wvid = (blockIdx.x * blockDim.x + threadIdx.x) >> 6;
  int lane = threadIdx.x & 63, w = threadIdx.x >> 6;
  int nw = (gridDim.x * blockDim.x) >> 6;
  float m = *mp;
  float acc[8] = {0, 0, 0, 0, 0, 0, 0, 0};
  float zs = 0.f;
  for (int n = wvid; n < NN; n += nw) {
    float wt = __expf(s[n] - m);
    u16x8 v = *(const u16x8*)(x + (size_t)n * HH + lane * 8);
#pragma unroll
    for (int i = 0; i < 8; ++i) acc[i] += wt * b2f(v[i]);
    zs += wt;
  }
  __shared__ float sm[2048];
  __shared__ float sz[4];
#pragma unroll
  for (int i = 0; i < 8; ++i) sm[w * 512 + lane * 8 + i] = acc[i];
  if (lane == 0) sz[w] = zs;
  __syncthreads();
  int t = threadIdx.x;
  for (int c = t; c < HH; c += 256) {
    float v2 = sm[c] + sm[512 + c] + sm[1024 + c] + sm[1536 + c];
    atomicAdd(&wx[c], v2);
  }
  if (t == 0) atomicAdd(Zp, sz[0] + sz[1] + sz[2] + sz[3]);
}

__global__ void k_gterm(const float* __restrict__ wx, const float* __restrict__ Zp,
                        const float* __restrict__ Wv, const float* __restrict__ Wg,
                        float* __restrict__ gterm) {
  __shared__ float gv[HH];
  __shared__ float g[HH];
  int t = threadIdx.x;
  float Z = *Zp;
  gv[t] = wx[t] / Z;
  __syncthreads();
  float s = 0.f;
  for (int i = 0; i < HH; ++i) s += gv[i] * Wv[(size_t)i * HH + t];
  g[t] = s;
  __syncthreads();
  float s2 = 0.f;
  for (int i = 0; i < HH; ++i) s2 += g[i] * Wg[(size_t)i * HH + t];
  gterm[t] = s2;
}

// ---------------- SpMM: agg = (A_r @ x + P_r @ Wpos) * invc ----------------
__global__ void k_spmm(const int* __restrict__ offs, const int* __restrict__ csr,
                       const float* __restrict__ invc, const float* __restrict__ P,
                       const float* __restrict__ wpos, const u16* __restrict__ x,
                       u16* __restrict__ agg) {
  int wv = (blockIdx.x * blockDim.x + threadIdx.x) >> 6;
  if (wv >= NN) return;
  int lane = threadIdx.x & 63;
  int beg = offs[wv], end = offs[wv + 1];
  float acc[8] = {0, 0, 0, 0, 0, 0, 0, 0};
  for (int k = beg; k < end; ++k) {
    int s = csr[k];
    u16x8 v = *(const u16x8*)(x + (size_t)s * HH + lane * 8);
#pragma unroll
    for (int i = 0; i < 8; ++i) acc[i] += b2f(v[i]);
  }
  float px = P[2 * wv], py = P[2 * wv + 1];
  float ic = invc[wv];
  u16x8 o;
#pragma unroll
  for (int i = 0; i < 8; ++i) {
    float w0 = wpos[lane * 8 + i];
    float w1 = wpos[HH + lane * 8 + i];
    float r = (acc[i] + px * w0 + py * w1) * ic;
    o[i] = f2b(r);
  }
  *(u16x8*)(agg + (size_t)wv * HH + lane * 8) = o;
}

// ---------------- GEMM: C = concat_k(A0..A3) @ concat_k(B0..B3)^T-weights ----------------
// A sources: [MP][512] bf16 row-major. B sources: B^T [n][k] bf16, row stride 512.
// mode 0: outB[row*512+col] = bf16(leaky(C*alpha + gvec[col]))   (all MP rows)
// mode 1: outF[row*Nout+col] = C + bias[col]   (row<M, col<Nout)
__global__ __launch_bounds__(256) void k_gemm(
    const u16* __restrict__ A0, const u16* __restrict__ A1,
    const u16* __restrict__ A2, const u16* __restrict__ A3,
    const u16* __restrict__ B0, const u16* __restrict__ B1,
    const u16* __restrict__ B2, const u16* __restrict__ B3,
    int nkt, int mode, float alpha, const float* __restrict__ gvec,
    u16* __restrict__ outB, float* __restrict__ outF,
    const float* __restrict__ bias, int M, int Nout)
{
  __shared__ u16 lsA[128 * 64];
  __shared__ u16 lsB[128 * 64];
  const int tid = threadIdx.x;
  const int wave = tid >> 6, lane = tid & 63;
  const int wm = (wave >> 1) * 64, wn = (wave & 1) * 64;
  const int rowM0 = blockIdx.y * 128, colN0 = blockIdx.x * 128;

  f32x4 acc[4][4];
#pragma unroll
  for (int i = 0; i < 4; ++i)
#pragma unroll
    for (int j = 0; j < 4; ++j) acc[i][j] = (f32x4){0.f, 0.f, 0.f, 0.f};

  const int rowT = wave * 8 + (lane >> 3);
  const int c8 = lane & 7;

  for (int kt = 0; kt < nkt; ++kt) {
    const int kbuf = kt >> 3;
    const int koff = (kt & 7) * 64;
    const u16* As = kbuf == 0 ? A0 : (kbuf == 1 ? A1 : (kbuf == 2 ? A2 : A3));
    const u16* Bs = kbuf == 0 ? B0 : (kbuf == 1 ? B1 : (kbuf == 2 ? B2 : B3));
#pragma unroll
    for (int i = 0; i < 4; ++i) {
      const int r = i * 32 + rowT;
      const int scol = (c8 ^ (r & 7)) * 8;   // inverse-swizzled global source (rule #21)
      async16(As + (size_t)(rowM0 + r) * HH + koff + scol, &lsA[i * 2048 + wave * 512]);
      async16(Bs + (size_t)(colN0 + r) * HH + koff + scol, &lsB[i * 2048 + wave * 512]);
    }
    __syncthreads();   // compiler drains vmcnt before s_barrier
#pragma unroll
    for (int K0 = 0; K0 < 2; ++K0) {
      s16x8 af[4], bfr[4];
      const int cb = K0 * 4 + (lane >> 4);
#pragma unroll
      for (int f = 0; f < 4; ++f) {
        const int mm = wm + f * 16 + (lane & 15);
        af[f] = *(const s16x8*)&lsA[mm * 64 + ((cb ^ (mm & 7)) << 3)];  // swizzled read
        const int nn = wn + f * 16 + (lane & 15);
        bfr[f] = *(const s16x8*)&lsB[nn * 64 + ((cb ^ (nn & 7)) << 3)];
      }
#pragma unroll
      for (int fm = 0; fm < 4; ++fm)
#pragma unroll
        for (int fn = 0; fn < 4; ++fn)
          acc[fm][fn] = __builtin_amdgcn_mfma_f32_16x16x32_bf16(af[fm], bfr[fn], acc[fm][fn], 0, 0, 0);
    }
    __syncthreads();
  }

#pragma unroll
  for (int fm = 0; fm < 4; ++fm) {
#pragma unroll
    for (int fn = 0; fn < 4; ++fn) {
#pragma unroll
      for (int r = 0; r < 4; ++r) {
        const int row = rowM0 + wm + fm * 16 + ((lane >> 4) << 2) + r;  // m89 C/D layout
        const int col = colN0 + wn + fn * 16 + (lane & 15);
        float v = acc[fm][fn][r];
        if (mode == 0) {
          v = v * alpha + (gvec ? gvec[col] : 0.f);
          outB[(size_t)row * HH + col] = f2b(leakyf(v));
        } else {
          if (row < M && col < Nout) outF[(size_t)row * Nout + col] = v + bias[col];
        }
      }
    }
  }
}

// ---------------- host ----------------
extern "C" void kernel_launch(void* const* d_in, const int* in_sizes, int n_in,
                              void* d_out, int out_size, void* d_ws, size_t ws_size,
                              hipStream_t stream) {
  (void)in_sizes; (void)n_in; (void)out_size;
  const float* x_window = (const float*)d_in[0];
  const float* x_pos    = (const float*)d_in[1];
  const int*   e_ptr[3] = {(const int*)d_in[2], (const int*)d_in[3], (const int*)d_in[4]};
  const float* W_pre  = (const float*)d_in[5];
  const float* W_post = (const float*)d_in[6];
  const float* Wl   = (const float*)d_in[7];
  const float* Wr   = (const float*)d_in[8];
  const float* Wpos = (const float*)d_in[9];
  const float* Wg   = (const float*)d_in[10];
  const float* seed = (const float*)d_in[11];
  const float* Wk   = (const float*)d_in[12];
  const float* Wv   = (const float*)d_in[13];
  const float* W_out= (const float*)d_in[14];
  const float* b_out= (const float*)d_in[15];
  float* out = (float*)d_out;

  char* base = (char*)d_ws;
  size_t off = 0;
  auto alloc = [&](size_t bytes) -> char* {
    char* p = base + off;
    off += (bytes + 255) & ~(size_t)255;
    return p;
  };
  u16* x_a   = (u16*)alloc((size_t)MP * HH * 2);
  u16* x_b   = (u16*)alloc((size_t)MP * HH * 2);
  u16* agg0  = (u16*)alloc((size_t)MP * HH * 2);
  u16* agg1  = (u16*)alloc((size_t)MP * HH * 2);
  u16* agg2  = (u16*)alloc((size_t)MP * HH * 2);
  u16* wlT   = (u16*)alloc((size_t)12 * HH2 * 2);
  u16* wrsT  = (u16*)alloc((size_t)4 * HH2 * 2);
  u16* wpreT = (u16*)alloc((size_t)HH2 * 2);
  u16* wpostT= (u16*)alloc((size_t)HH2 * 2);
  u16* woutT = (u16*)alloc((size_t)256 * HH * 2);
  int* offs  = (int*)alloc((size_t)3 * (NN + 1) * 4);
  int* curs  = (int*)alloc((size_t)3 * NN * 4);
  int* cnt   = (int*)alloc((size_t)3 * NN * 4);
  int* csr   = (int*)alloc((size_t)3 * EE * 4);
  float* invc = (float*)alloc((size_t)3 * NN * 4);
  float* P    = (float*)alloc((size_t)3 * NN * 2 * 4);
  float* scores   = (float*)alloc((size_t)NN * 4);
  float* partials = (float*)alloc(512 * 4);
  float* kvec  = (float*)alloc(HH * 4);
  float* wx    = (float*)alloc((HH + 1) * 4);   // wx[512], then Z
  float* gterm = (float*)alloc(HH * 4);
  float* mbuf  = (float*)alloc(4);
  if (off > ws_size) return;   // fail loudly (validation will catch) rather than corrupt

  hipMemsetAsync(cnt, 0, (size_t)3 * NN * 4, stream);
  hipMemsetAsync(P, 0, (size_t)3 * NN * 2 * 4, stream);

  for (int r = 0; r < 3; ++r)
    k_hist<<<(EE + 255) / 256, 256, 0, stream>>>(e_ptr[r] + EE, cnt + r * NN);
  for (int r = 0; r < 3; ++r)
    k_scan<<<1, 1024, 0, stream>>>(cnt + r * NN, offs + r * (NN + 1), curs + r * NN, NN);
  for (int r = 0; r < 3; ++r)
    k_fill<<<(EE + 255) / 256, 256, 0, stream>>>(e_ptr[r], e_ptr[r] + EE,
                                                 (const float2*)x_pos,
                                                 curs + r * NN, csr + r * EE, P + r * NN * 2);
  for (int r = 0; r < 3; ++r)
    k_invc<<<(NN + 255) / 256, 256, 0, stream>>>(offs + r * (NN + 1), invc + r * NN);

  k_transpose_many<<<12 * HH2 / 256, 256, 0, stream>>>(Wl, wlT, 12);
  k_sum3_all<<<4 * HH2 / 256, 256, 0, stream>>>(Wr, wrsT);
  k_transpose_many<<<HH2 / 256, 256, 0, stream>>>(W_pre, wpreT, 1);
  k_transpose_many<<<HH2 / 256, 256, 0, stream>>>(W_post, wpostT, 1);
  k_transpose_pad<<<(HH * 256) / 256, 256, 0, stream>>>(W_out, woutT, HH, OUTC, 256);

  k_cvt<<<(NN * HH / 8 + 255) / 256, 256, 0, stream>>>(x_window, x_b, NN * HH / 8);
  k_zero_pads<<<((MP - NN) * HH * 5 + 255) / 256, 256, 0, stream>>>(x_a, x_b, agg0, agg1, agg2);

  const u16* nul = nullptr;
  // pretransform: t = leaky(xw @ W_pre) -> agg0 ; x0 = leaky(t @ W_post) -> x_a
  k_gemm<<<dim3(4, 391), 256, 0, stream>>>(x_b, nul, nul, nul, wpreT, nul, nul, nul,
                                           8, 0, 1.f, nullptr, agg0, nullptr, nullptr, NN, HH);
  k_gemm<<<dim3(4, 391), 256, 0, stream>>>(agg0, nul, nul, nul, wpostT, nul, nul, nul,
                                           8, 0, 1.f, nullptr, x_a, nullptr, nullptr, NN, HH);

  u16* cur = x_a; u16* nxt = x_b;
  u16* aggp[3] = {agg0, agg1, agg2};
  for (int l = 0; l < LL; ++l) {
    k_kvec<<<1, 512, 0, stream>>>(Wk + (size_t)l * HH2, seed + (size_t)l * HH, kvec);
    k_scores<<<512, 256, 0, stream>>>(cur, kvec, scores, partials);
    k_maxr<<<1, 512, 0, stream>>>(partials, mbuf);
    hipMemsetAsync(wx, 0, (HH + 1) * 4, stream);
    k_wsum<<<512, 256, 0, stream>>>(cur, scores, mbuf, wx, wx + HH);
    k_gterm<<<1, 512, 0, stream>>>(wx, wx + HH, Wv + (size_t)l * HH2, Wg + (size_t)l * HH2, gterm);
    for (int r = 0; r < 3; ++r)
      k_spmm<<<NN / 4, 256, 0, stream>>>(offs + r * (NN + 1), csr + r * EE, invc + r * NN,
                                         P + r * NN * 2, Wpos + (size_t)(l * 3 + r) * 2 * HH,
                                         cur, aggp[r]);
    k_gemm<<<dim3(4, 391), 256, 0, stream>>>(
        agg0, agg1, agg2, cur,
        wlT + (size_t)(l * 3 + 0) * HH2, wlT + (size_t)(l * 3 + 1) * HH2,
        wlT + (size_t)(l * 3 + 2) * HH2, wrsT + (size_t)l * HH2,
        32, 0, (1.f / 3.f), gterm, nxt, nullptr, nullptr, NN, HH);
    u16* t = cur; cur = nxt; nxt = t;
  }
  // final projection: out = x @ W_out + b_out
  k_gemm<<<dim3(2, 391), 256, 0, stream>>>(cur, nul, nul, nul, woutT, nul, nul, nul,
                                           8, 1, 1.f, nullptr, nullptr, out, b_out, NN, OUTC);
}

// Round 2
// 2650.392 us; speedup vs baseline: 1.0516x; 1.0516x over previous
//
#include <hip/hip_runtime.h>

#define NN 50000
#define EE 400000
#define HH 512
#define LL 4
#define OUTC 250
#define MP 50048               // NN padded to multiple of 128
#define HH2 (HH*HH)
#define NPW 512                // pooling partial waves
#define INV_SQRT_H 0.044194173824159216f

typedef unsigned short u16;
typedef __attribute__((ext_vector_type(8))) unsigned short u16x8;
typedef __attribute__((ext_vector_type(8))) short s16x8;
typedef __attribute__((ext_vector_type(4))) float f32x4;

__device__ __forceinline__ float b2f(u16 v) {
  union { unsigned u; float f; } c; c.u = ((unsigned)v) << 16; return c.f;
}
__device__ __forceinline__ u16 f2b(float f) {
  union { float f; unsigned u; } c; c.f = f;
  unsigned r = c.u + 0x7fffu + ((c.u >> 16) & 1u);
  return (u16)(r >> 16);
}
__device__ __forceinline__ float leakyf(float v) { return v > 0.f ? v : 0.2f * v; }

__device__ __forceinline__ void async16(const void* g, void* l) {
  __builtin_amdgcn_global_load_lds((const __attribute__((address_space(1))) void*)g,
                                   (__attribute__((address_space(3))) void*)l,
                                   16, 0, 0);
}

// ---------------- CSR build (batched over 3 relations) ----------------
__global__ void k_hist(const int* __restrict__ e0, const int* __restrict__ e1,
                       const int* __restrict__ e2, int* __restrict__ cnt) {
  int r = blockIdx.y;
  const int* dst = (r == 0 ? e0 : r == 1 ? e1 : e2) + EE;
  int i = blockIdx.x * 256 + threadIdx.x;
  if (i < EE) atomicAdd(&cnt[r * NN + dst[i]], 1);
}

__global__ void k_scan(const int* __restrict__ cnt_all, int* __restrict__ offs_all,
                       int* __restrict__ cursor_all, int n) {
  const int r = blockIdx.x;
  const int* cnt = cnt_all + r * n;
  int* offs = offs_all + r * (n + 1);
  int* cursor = cursor_all + r * n;
  __shared__ int sm[1024];
  __shared__ int carrysh;
  int t = threadIdx.x;
  if (t == 0) carrysh = 0;
  __syncthreads();
  for (int base = 0; base < n; base += 1024) {
    int v = (base + t < n) ? cnt[base + t] : 0;
    sm[t] = v;
    __syncthreads();
#pragma unroll
    for (int d = 1; d < 1024; d <<= 1) {
      int u = (t >= d) ? sm[t - d] : 0;
      __syncthreads();
      sm[t] += u;
      __syncthreads();
    }
    int incl = sm[t];
    int carry = carrysh;
    if (base + t < n) { int ex = carry + incl - v; offs[base + t] = ex; cursor[base + t] = ex; }
    __syncthreads();
    if (t == 1023) carrysh = carry + incl;
    __syncthreads();
  }
  if (t == 0) offs[n] = carrysh;
}

__global__ void k_fill(const int* __restrict__ e0, const int* __restrict__ e1,
                       const int* __restrict__ e2, const float2* __restrict__ pos,
                       int* __restrict__ cursor, int* __restrict__ csr, float* __restrict__ P) {
  int r = blockIdx.y;
  const int* ep = (r == 0 ? e0 : r == 1 ? e1 : e2);
  int i = blockIdx.x * 256 + threadIdx.x;
  if (i >= EE) return;
  int s = ep[i], d = ep[EE + i];
  int slot = atomicAdd(&cursor[r * NN + d], 1);
  csr[r * EE + slot] = s;
  float2 a = pos[s], b = pos[d];
  atomicAdd(&P[r * NN * 2 + 2 * d], a.x - b.x);
  atomicAdd(&P[r * NN * 2 + 2 * d + 1], a.y - b.y);
}

__global__ void k_invc(const int* __restrict__ offs, float* __restrict__ invc) {
  int r = blockIdx.y;
  int i = blockIdx.x * 256 + threadIdx.x;
  if (i >= NN) return;
  const int* o = offs + r * (NN + 1);
  int c = o[i + 1] - o[i];
  invc[r * NN + i] = 1.f / (float)(c > 1 ? c : 1);
}

// ---------------- weight prep (f32 -> bf16, transposed to [n][k]) ----------------
__global__ void k_transpose_many(const float* __restrict__ W, u16* __restrict__ WT, int nmat) {
  long idx = (long)blockIdx.x * 256 + threadIdx.x;
  if (idx >= (long)nmat * HH2) return;
  int m = (int)(idx / HH2);
  int rem = (int)(idx - (long)m * HH2);
  int r = rem % HH, c = rem / HH;
  WT[(size_t)m * HH2 + (size_t)c * HH + r] = f2b(W[(size_t)m * HH2 + (size_t)r * HH + c]);
}

__global__ void k_sum3_all(const float* __restrict__ Wr, u16* __restrict__ WT) {
  long idx = (long)blockIdx.x * 256 + threadIdx.x;
  if (idx >= 4L * HH2) return;
  int l = (int)(idx / HH2);
  int rem = (int)(idx - (long)l * HH2);
  int r = rem % HH, c = rem / HH;
  const float* W3 = Wr + (size_t)l * 3 * HH2;
  float v = W3[(size_t)r * HH + c] + W3[(size_t)HH2 + (size_t)r * HH + c] +
            W3[(size_t)2 * HH2 + (size_t)r * HH + c];
  WT[(size_t)l * HH2 + (size_t)c * HH + r] = f2b(v);
}

__global__ void k_transpose_pad(const float* __restrict__ W, u16* __restrict__ WT,
                                int rows, int cols, int tcols) {
  int idx = blockIdx.x * 256 + threadIdx.x;
  if (idx >= rows * tcols) return;
  int r = idx % rows, c = idx / rows;
  float v = (c < cols) ? W[(size_t)r * cols + c] : 0.f;
  WT[(size_t)c * rows + r] = f2b(v);
}

// ---------------- misc ----------------
__global__ void k_cvt(const float* __restrict__ in, u16* __restrict__ out, int n8) {
  int i = blockIdx.x * 256 + threadIdx.x;
  if (i >= n8) return;
  const float4 a = *(const float4*)(in + (size_t)i * 8);
  const float4 b = *(const float4*)(in + (size_t)i * 8 + 4);
  u16x8 o;
  o[0] = f2b(a.x); o[1] = f2b(a.y); o[2] = f2b(a.z); o[3] = f2b(a.w);
  o[4] = f2b(b.x); o[5] = f2b(b.y); o[6] = f2b(b.z); o[7] = f2b(b.w);
  *(u16x8*)(out + (size_t)i * 8) = o;
}

__global__ void k_zero_pads(u16* a, u16* b, u16* c, u16* d, u16* e) {
  int i = blockIdx.x * 256 + threadIdx.x;
  const int per = (MP - NN) * HH;
  if (i >= per * 5) return;
  int sel = i / per, rem = i - sel * per;
  u16* p = sel == 0 ? a : sel == 1 ? b : sel == 2 ? c : sel == 3 ? d : e;
  p[(size_t)NN * HH + rem] = 0;
}

// ---------------- pooling ----------------
__global__ void k_kvec(const float* __restrict__ Wk, const float* __restrict__ seed,
                       float* __restrict__ kvec) {
  int l = blockIdx.x;
  const float* Wkl = Wk + (size_t)l * HH2;
  const float* sdl = seed + (size_t)l * HH;
  float* kv = kvec + (size_t)l * HH;
  int w = threadIdx.x >> 6, lane = threadIdx.x & 63;
  float sv[8];
#pragma unroll
  for (int i = 0; i < 8; ++i) sv[i] = sdl[lane * 8 + i];
  for (int row = w; row < HH; row += 8) {
    const float* p = Wkl + (size_t)row * HH + lane * 8;
    float d = 0.f;
#pragma unroll
    for (int i = 0; i < 8; ++i) d += p[i] * sv[i];
#pragma unroll
    for (int o = 32; o > 0; o >>= 1) d += __shfl_xor(d, o);
    if (lane == 0) kv[row] = d;
  }
}

// one pass over x: per-wave online softmax-weighted sum.
// part[w][0]=m, [1]=Z, [2..513]=acc
__global__ void k_pool1(const u16* __restrict__ x, const float* __restrict__ kvec,
                        float* __restrict__ part) {
  int gw = (blockIdx.x * 256 + threadIdx.x) >> 6;
  int lane = threadIdx.x & 63;
  float kl[8];
#pragma unroll
  for (int i = 0; i < 8; ++i) kl[i] = kvec[lane * 8 + i];
  float m = -1e30f, Z = 0.f;
  float acc[8] = {0, 0, 0, 0, 0, 0, 0, 0};
  for (int n = gw; n < NN; n += NPW) {
    u16x8 v = *(const u16x8*)(x + (size_t)n * HH + lane * 8);
    float xl[8], d = 0.f;
#pragma unroll
    for (int i = 0; i < 8; ++i) { xl[i] = b2f(v[i]); d += xl[i] * kl[i]; }
#pragma unroll
    for (int o = 32; o > 0; o >>= 1) d += __shfl_xor(d, o);
    d *= INV_SQRT_H;
    float mn = fmaxf(m, d);
    float c = __expf(m - mn), w = __expf(d - mn);
    Z = Z * c + w;
#pragma unroll
    for (int i = 0; i < 8; ++i) acc[i] = acc[i] * c + w * xl[i];
    m = mn;
  }
  float* p = part + (size_t)gw * 514;
#pragma unroll
  for (int i = 0; i < 8; ++i) p[2 + lane * 8 + i] = acc[i];
  if (lane == 0) { p[0] = m; p[1] = Z; }
}

// combine partials -> gv, then gterm = (gv @ Wv) @ Wg
__global__ void k_pool2g(const float* __restrict__ part, const float* __restrict__ Wv,
                         const float* __restrict__ Wg, float* __restrict__ gterm) {
  __shared__ float red[512];
  __shared__ float gv[HH];
  __shared__ float g[HH];
  int t = threadIdx.x;
  float m = fmaxf(part[(size_t)t * 514], part[(size_t)(t + 512 < NPW ? t + 512 : t) * 514]);
  red[t] = m;
  __syncthreads();
  for (int s = 256; s > 0; s >>= 1) {
    if (t < s) red[t] = fmaxf(red[t], red[t + s]);
    __syncthreads();
  }
  float M = red[0];
  __syncthreads();
  float s = 0.f, z = 0.f;
  for (int w = 0; w < NPW; ++w) {
    const float* p = part + (size_t)w * 514;
    float e = __expf(p[0] - M);
    z += e * p[1];
    s += e * p[2 + t];
  }
  gv[t] = s / z;
  __syncthreads();
  float a = 0.f;
  for (int i = 0; i < HH; ++i) a += gv[i] * Wv[(size_t)i * HH + t];
  g[t] = a;
  __syncthreads();
  float b = 0.f;
  for (int i = 0; i < HH; ++i) b += g[i] * Wg[(size_t)i * HH + t];
  gterm[t] = b;
}

// ---------------- SpMM: agg_r = (A_r @ x + P_r @ Wpos_r) * invc_r, batched over r ----------------
__global__ void k_spmm(const int* __restrict__ offs, const int* __restrict__ csr,
                       const float* __restrict__ invc, const float* __restrict__ P,
                       const float* __restrict__ wposL, const u16* __restrict__ x,
                       u16* __restrict__ agg) {
  int r = blockIdx.y;
  int wv = (blockIdx.x * 256 + threadIdx.x) >> 6;
  if (wv >= NN) return;
  int lane = threadIdx.x & 63;
  const int* o = offs + r * (NN + 1);
  const int* cs = csr + (size_t)r * EE;
  const float* wpos = wposL + (size_t)r * 2 * HH;
  int beg = o[wv], end = o[wv + 1];
  float acc[8] = {0, 0, 0, 0, 0, 0, 0, 0};
  for (int k = beg; k < end; ++k) {
    int s = cs[k];
    u16x8 v = *(const u16x8*)(x + (size_t)s * HH + lane * 8);
#pragma unroll
    for (int i = 0; i < 8; ++i) acc[i] += b2f(v[i]);
  }
  float px = P[(size_t)r * NN * 2 + 2 * wv], py = P[(size_t)r * NN * 2 + 2 * wv + 1];
  float ic = invc[(size_t)r * NN + wv];
  u16x8 out;
#pragma unroll
  for (int i = 0; i < 8; ++i) {
    float w0 = wpos[lane * 8 + i];
    float w1 = wpos[HH + lane * 8 + i];
    float v = (acc[i] + px * w0 + py * w1) * ic;
    out[i] = f2b(v);
  }
  *(u16x8*)(agg + ((size_t)r * MP + wv) * HH + lane * 8) = out;
}

// ---------------- wide GEMM: 128 x BN tile, 8 waves, full-N (no A re-read) ----------------
// A sources: [MP][512] bf16 row-major, selected by kt>>3. B: B^T [n][k] bf16, row stride 512.
// mode 0: outB[row*512+col] = bf16(leaky(C*alpha + gvec[col]))
// mode 1: outF[row*Nout+col] = C + bias[col]   (row<M, col<Nout)
template <int BN>
__global__ __launch_bounds__(512, 2) void k_gemm_w(
    const u16* __restrict__ A0, const u16* __restrict__ A1,
    const u16* __restrict__ A2, const u16* __restrict__ A3,
    const u16* __restrict__ B0, const u16* __restrict__ B1,
    const u16* __restrict__ B2, const u16* __restrict__ B3,
    int nkt, int mode, float alpha, const float* __restrict__ gvec,
    u16* __restrict__ outB, float* __restrict__ outF,
    const float* __restrict__ bias, int M, int Nout)
{
  constexpr int FN = BN / 64;          // N fragments per wave
  __shared__ u16 lsA[128 * 64];
  __shared__ u16 lsB[BN * 64];
  const int tid = threadIdx.x;
  const int wave = tid >> 6, lane = tid & 63;
  const int wm = (wave >> 2) * 64;
  const int wn = (wave & 3) * (BN / 4);
  const int rowM0 = blockIdx.y * 128;

  f32x4 acc[4][FN];
#pragma unroll
  for (int i = 0; i < 4; ++i)
#pragma unroll
    for (int j = 0; j < FN; ++j) acc[i][j] = (f32x4){0.f, 0.f, 0.f, 0.f};

  const int rlane = lane >> 3;   // 0..7 row within 8-row chunk
  const int c8 = lane & 7;       // 16B column unit

  for (int kt = 0; kt < nkt; ++kt) {
    const int kbuf = kt >> 3;
    const int koff = (kt & 7) * 64;
    const u16* As = kbuf == 0 ? A0 : (kbuf == 1 ? A1 : (kbuf == 2 ? A2 : A3));
    const u16* Bs = kbuf == 0 ? B0 : (kbuf == 1 ? B1 : (kbuf == 2 ? B2 : B3));
    // A tile: 128 rows = 16 chunks of 8 rows; each wave stages 2
#pragma unroll
    for (int i = 0; i < 2; ++i) {
      const int chunk = i * 8 + wave;
      const int r = chunk * 8 + rlane;
      const int scol = (c8 ^ (r & 7)) * 8;   // inverse-swizzled global source
      async16(As + (size_t)(rowM0 + r) * HH + koff + scol, &lsA[chunk * 512]);
    }
    // B tile: BN rows = BN/8 chunks; each wave stages BN/64
#pragma unroll
    for (int i = 0; i < BN / 64; ++i) {
      const int chunk = i * 8 + wave;
      const int r = chunk * 8 + rlane;
      const int scol = (c8 ^ (r & 7)) * 8;
      async16(Bs + (size_t)r * HH + koff + scol, &lsB[chunk * 512]);
    }
    __syncthreads();
#pragma unroll
    for (int K0 = 0; K0 < 2; ++K0) {
      const int cb = K0 * 4 + (lane >> 4);
      s16x8 af[4];
#pragma unroll
      for (int f = 0; f < 4; ++f) {
        const int mm = wm + f * 16 + (lane & 15);
        af[f] = *(const s16x8*)&lsA[mm * 64 + ((cb ^ (mm & 7)) << 3)];  // swizzled read
      }
#pragma unroll
      for (int fn = 0; fn < FN; ++fn) {
        const int nn = wn + fn * 16 + (lane & 15);
        s16x8 bf = *(const s16x8*)&lsB[nn * 64 + ((cb ^ (nn & 7)) << 3)];
#pragma unroll
        for (int fm = 0; fm < 4; ++fm)
          acc[fm][fn] = __builtin_amdgcn_mfma_f32_16x16x32_bf16(af[fm], bf, acc[fm][fn], 0, 0, 0);
      }
    }
    __syncthreads();
  }

#pragma unroll
  for (int fm = 0; fm < 4; ++fm) {
#pragma unroll
    for (int fn = 0; fn < FN; ++fn) {
#pragma unroll
      for (int r = 0; r < 4; ++r) {
        const int row = rowM0 + wm + fm * 16 + ((lane >> 4) << 2) + r;  // m89 C/D layout
        const int col = wn + fn * 16 + (lane & 15);
        float v = acc[fm][fn][r];
        if (mode == 0) {
          v = v * alpha + (gvec ? gvec[col] : 0.f);
          outB[(size_t)row * HH + col] = f2b(leakyf(v));
        } else {
          if (row < M && col < Nout) outF[(size_t)row * Nout + col] = v + (bias ? bias[col] : 0.f);
        }
      }
    }
  }
}

// ---------------- host ----------------
extern "C" void kernel_launch(void* const* d_in, const int* in_sizes, int n_in,
                              void* d_out, int out_size, void* d_ws, size_t ws_size,
                              hipStream_t stream) {
  (void)in_sizes; (void)n_in; (void)out_size;
  const float* x_window = (const float*)d_in[0];
  const float* x_pos    = (const float*)d_in[1];
  const int*   e0 = (const int*)d_in[2];
  const int*   e1 = (const int*)d_in[3];
  const int*   e2 = (const int*)d_in[4];
  const float* W_pre  = (const float*)d_in[5];
  const float* W_post = (const float*)d_in[6];
  const float* Wl   = (const float*)d_in[7];
  const float* Wr   = (const float*)d_in[8];
  const float* Wpos = (const float*)d_in[9];
  const float* Wg   = (const float*)d_in[10];
  const float* seed = (const float*)d_in[11];
  const float* Wk   = (const float*)d_in[12];
  const float* Wv   = (const float*)d_in[13];
  const float* W_out= (const float*)d_in[14];
  const float* b_out= (const float*)d_in[15];
  float* out = (float*)d_out;

  char* base = (char*)d_ws;
  size_t off = 0;
  auto alloc = [&](size_t bytes) -> char* {
    char* p = base + off;
    off += (bytes + 255) & ~(size_t)255;
    return p;
  };
  u16* x_a   = (u16*)alloc((size_t)MP * HH * 2);
  u16* x_b   = (u16*)alloc((size_t)MP * HH * 2);
  u16* agg0  = (u16*)alloc((size_t)MP * HH * 2);   // agg0..agg2 contiguous
  u16* agg1  = (u16*)alloc((size_t)MP * HH * 2);
  u16* agg2  = (u16*)alloc((size_t)MP * HH * 2);
  (void)agg1; (void)agg2;
  u16* wlT   = (u16*)alloc((size_t)12 * HH2 * 2);
  u16* wrsT  = (u16*)alloc((size_t)4 * HH2 * 2);
  u16* wpreT = (u16*)alloc((size_t)HH2 * 2);
  u16* wpostT= (u16*)alloc((size_t)HH2 * 2);
  u16* woutT = (u16*)alloc((size_t)256 * HH * 2);
  int* offs  = (int*)alloc((size_t)3 * (NN + 1) * 4);
  int* curs  = (int*)alloc((size_t)3 * NN * 4);    // dead after CSR build
  int* cnt   = (int*)alloc((size_t)3 * NN * 4);    // dead after CSR build
  int* csr   = (int*)alloc((size_t)3 * EE * 4);
  float* invc = (float*)alloc((size_t)3 * NN * 4);
  float* P    = (float*)alloc((size_t)3 * NN * 2 * 4);
  float* kvec  = (float*)alloc((size_t)LL * HH * 4);
  float* gterm = (float*)alloc(HH * 4);
  float* part  = (float*)curs;   // overlay: NPW*514*4 = 1.05 MB fits in curs+cnt (1.2 MB)
  if (off > ws_size) return;

  hipMemsetAsync(cnt, 0, (size_t)3 * NN * 4, stream);
  hipMemsetAsync(P, 0, (size_t)3 * NN * 2 * 4, stream);

  k_hist<<<dim3((EE + 255) / 256, 3), 256, 0, stream>>>(e0, e1, e2, cnt);
  k_scan<<<3, 1024, 0, stream>>>(cnt, offs, curs, NN);
  k_fill<<<dim3((EE + 255) / 256, 3), 256, 0, stream>>>(e0, e1, e2, (const float2*)x_pos,
                                                        curs, csr, P);
  k_invc<<<dim3((NN + 255) / 256, 3), 256, 0, stream>>>(offs, invc);

  k_transpose_many<<<12 * HH2 / 256, 256, 0, stream>>>(Wl, wlT, 12);
  k_sum3_all<<<4 * HH2 / 256, 256, 0, stream>>>(Wr, wrsT);
  k_transpose_many<<<HH2 / 256, 256, 0, stream>>>(W_pre, wpreT, 1);
  k_transpose_many<<<HH2 / 256, 256, 0, stream>>>(W_post, wpostT, 1);
  k_transpose_pad<<<(HH * 256) / 256, 256, 0, stream>>>(W_out, woutT, HH, OUTC, 256);
  k_kvec<<<LL, 512, 0, stream>>>(Wk, seed, kvec);

  k_cvt<<<(NN * HH / 8 + 255) / 256, 256, 0, stream>>>(x_window, x_b, NN * HH / 8);
  k_zero_pads<<<((MP - NN) * HH * 5 + 255) / 256, 256, 0, stream>>>(x_a, x_b, agg0, agg1, agg2);

  const u16* nul = nullptr;
  // pretransform: t = leaky(xw @ W_pre) -> agg0 ; x0 = leaky(t @ W_post) -> x_a
  k_gemm_w<512><<<dim3(1, MP / 128), 512, 0, stream>>>(
      x_b, nul, nul, nul, wpreT, nul, nul, nul,
      8, 0, 1.f, nullptr, agg0, nullptr, nullptr, NN, HH);
  k_gemm_w<512><<<dim3(1, MP / 128), 512, 0, stream>>>(
      agg0, nul, nul, nul, wpostT, nul, nul, nul,
      8, 0, 1.f, nullptr, x_a, nullptr, nullptr, NN, HH);

  u16* cur = x_a; u16* nxt = x_b;
  for (int l = 0; l < LL; ++l) {
    k_pool1<<<NPW / 4, 256, 0, stream>>>(cur, kvec + (size_t)l * HH, part);
    k_pool2g<<<1, 512, 0, stream>>>(part, Wv + (size_t)l * HH2, Wg + (size_t)l * HH2, gterm);
    k_spmm<<<dim3(NN / 4, 3), 256, 0, stream>>>(offs, csr, invc, P,
                                                Wpos + (size_t)l * 3 * 2 * HH, cur, agg0);
    k_gemm_w<512><<<dim3(1, MP / 128), 512, 0, stream>>>(
        agg0, agg1, agg2, cur,
        wlT + (size_t)(l * 3 + 0) * HH2, wlT + (size_t)(l * 3 + 1) * HH2,
        wlT + (size_t)(l * 3 + 2) * HH2, wrsT + (size_t)l * HH2,
        32, 0, (1.f / 3.f), gterm, nxt, nullptr, nullptr, NN, HH);
    u16* t = cur; cur = nxt; nxt = t;
  }
  // final projection: out = x @ W_out + b_out
  k_gemm_w<256><<<dim3(1, MP / 128), 512, 0, stream>>>(
      cur, nul, nul, nul, woutT, nul, nul, nul,
      8, 1, 1.f, nullptr, nullptr, out, b_out, NN, OUTC);
}

// Round 3
// 2542.071 us; speedup vs baseline: 1.0964x; 1.0426x over previous
//
#include <hip/hip_runtime.h>

#define NN 50000
#define EE 400000
#define HH 512
#define LL 4
#define OUTC 250
#define MP 50048               // NN padded to multiple of 128
#define HH2 (HH*HH)
#define NPW 512                // pooling partial waves
#define NBLK 49                // ceil(NN/1024)
#define INV_SQRT_H 0.044194173824159216f

typedef unsigned short u16;
typedef __attribute__((ext_vector_type(8))) unsigned short u16x8;
typedef __attribute__((ext_vector_type(8))) short s16x8;
typedef __attribute__((ext_vector_type(4))) float f32x4;

__device__ __forceinline__ float b2f(u16 v) {
  union { unsigned u; float f; } c; c.u = ((unsigned)v) << 16; return c.f;
}
__device__ __forceinline__ u16 f2b(float f) {
  union { float f; unsigned u; } c; c.f = f;
  unsigned r = c.u + 0x7fffu + ((c.u >> 16) & 1u);
  return (u16)(r >> 16);
}
__device__ __forceinline__ float leakyf(float v) { return v > 0.f ? v : 0.2f * v; }

__device__ __forceinline__ void async16(const void* g, void* l) {
  __builtin_amdgcn_global_load_lds((const __attribute__((address_space(1))) void*)g,
                                   (__attribute__((address_space(3))) void*)l,
                                   16, 0, 0);
}

// ---------------- CSR build ----------------
__global__ void k_hist(const int* __restrict__ e0, const int* __restrict__ e1,
                       const int* __restrict__ e2, int* __restrict__ cnt) {
  int r = blockIdx.y;
  const int* dst = (r == 0 ? e0 : r == 1 ? e1 : e2) + EE;
  int i = blockIdx.x * 256 + threadIdx.x;
  if (i < EE) atomicAdd(&cnt[r * NN + dst[i]], 1);
}

// phase 1: per-block (1024) exclusive scan + block sums + invc
__global__ void k_scan1(const int* __restrict__ cnt, int* __restrict__ offs,
                        float* __restrict__ invc, int* __restrict__ bsum) {
  int r = blockIdx.y, b = blockIdx.x, t = threadIdx.x;
  int i = b * 1024 + t;
  int v = (i < NN) ? cnt[r * NN + i] : 0;
  __shared__ int sm[1024];
  sm[t] = v;
  __syncthreads();
#pragma unroll
  for (int d = 1; d < 1024; d <<= 1) {
    int u = (t >= d) ? sm[t - d] : 0;
    __syncthreads();
    sm[t] += u;
    __syncthreads();
  }
  if (i < NN) {
    offs[r * (NN + 1) + i] = sm[t] - v;          // local exclusive
    invc[r * NN + i] = 1.f / (float)(v > 1 ? v : 1);
  }
  if (t == 1023) bsum[r * NBLK + b] = sm[t];
}

// phase 2: exclusive-scan the 49 block sums per relation (one wave each)
__global__ void k_scan2(int* __restrict__ bsum) {
  int t = threadIdx.x;
  int r = t >> 6, lane = t & 63;
  if (r >= 3) return;
  int orig = (lane < NBLK) ? bsum[r * NBLK + lane] : 0;
  int v = orig;
#pragma unroll
  for (int d = 1; d < 64; d <<= 1) {
    int u = __shfl_up(v, d);
    if (lane >= d) v += u;
  }
  if (lane < NBLK) bsum[r * NBLK + lane] = v - orig;  // exclusive
}

// phase 3: add block offsets, init cursor, set offs[NN]=EE
__global__ void k_scan3(const int* __restrict__ bsum, int* __restrict__ offs,
                        int* __restrict__ cursor) {
  int r = blockIdx.y, b = blockIdx.x, t = threadIdx.x;
  int i = b * 1024 + t;
  if (i < NN) {
    int v = offs[r * (NN + 1) + i] + bsum[r * NBLK + b];
    offs[r * (NN + 1) + i] = v;
    cursor[r * NN + i] = v;
  }
  if (b == 0 && t == 0) offs[r * (NN + 1) + NN] = EE;
}

__global__ void k_fill(const int* __restrict__ e0, const int* __restrict__ e1,
                       const int* __restrict__ e2, const float2* __restrict__ pos,
                       int* __restrict__ cursor, int* __restrict__ csr, float* __restrict__ P) {
  int r = blockIdx.y;
  const int* ep = (r == 0 ? e0 : r == 1 ? e1 : e2);
  int i = blockIdx.x * 256 + threadIdx.x;
  if (i >= EE) return;
  int s = ep[i], d = ep[EE + i];
  int slot = atomicAdd(&cursor[r * NN + d], 1);
  csr[r * EE + slot] = s;
  float2 a = pos[s], b = pos[d];
  atomicAdd(&P[r * NN * 2 + 2 * d], a.x - b.x);
  atomicAdd(&P[r * NN * 2 + 2 * d + 1], a.y - b.y);
}

// ---------------- weight prep (f32 -> bf16, transposed to [n][k]) ----------------
__global__ void k_transpose_many(const float* __restrict__ W, u16* __restrict__ WT, int nmat) {
  long idx = (long)blockIdx.x * 256 + threadIdx.x;
  if (idx >= (long)nmat * HH2) return;
  int m = (int)(idx / HH2);
  int rem = (int)(idx - (long)m * HH2);
  int r = rem % HH, c = rem / HH;
  WT[(size_t)m * HH2 + (size_t)c * HH + r] = f2b(W[(size_t)m * HH2 + (size_t)r * HH + c]);
}

__global__ void k_sum3_all(const float* __restrict__ Wr, u16* __restrict__ WT) {
  long idx = (long)blockIdx.x * 256 + threadIdx.x;
  if (idx >= 4L * HH2) return;
  int l = (int)(idx / HH2);
  int rem = (int)(idx - (long)l * HH2);
  int r = rem % HH, c = rem / HH;
  const float* W3 = Wr + (size_t)l * 3 * HH2;
  float v = W3[(size_t)r * HH + c] + W3[(size_t)HH2 + (size_t)r * HH + c] +
            W3[(size_t)2 * HH2 + (size_t)r * HH + c];
  WT[(size_t)l * HH2 + (size_t)c * HH + r] = f2b(v);
}

__global__ void k_transpose_pad(const float* __restrict__ W, u16* __restrict__ WT,
                                int rows, int cols, int tcols) {
  int idx = blockIdx.x * 256 + threadIdx.x;
  if (idx >= rows * tcols) return;
  int r = idx % rows, c = idx / rows;
  float v = (c < cols) ? W[(size_t)r * cols + c] : 0.f;
  WT[(size_t)c * rows + r] = f2b(v);
}

// ---------------- misc ----------------
__global__ void k_cvt(const float* __restrict__ in, u16* __restrict__ out, int n8) {
  int i = blockIdx.x * 256 + threadIdx.x;
  if (i >= n8) return;
  const float4 a = *(const float4*)(in + (size_t)i * 8);
  const float4 b = *(const float4*)(in + (size_t)i * 8 + 4);
  u16x8 o;
  o[0] = f2b(a.x); o[1] = f2b(a.y); o[2] = f2b(a.z); o[3] = f2b(a.w);
  o[4] = f2b(b.x); o[5] = f2b(b.y); o[6] = f2b(b.z); o[7] = f2b(b.w);
  *(u16x8*)(out + (size_t)i * 8) = o;
}

__global__ void k_zero_pads(u16* a, u16* b, u16* c, u16* d, u16* e) {
  int i = blockIdx.x * 256 + threadIdx.x;
  const int per = (MP - NN) * HH;
  if (i >= per * 5) return;
  int sel = i / per, rem = i - sel * per;
  u16* p = sel == 0 ? a : sel == 1 ? b : sel == 2 ? c : sel == 3 ? d : e;
  p[(size_t)NN * HH + rem] = 0;
}

// ---------------- pooling ----------------
__global__ void k_kvec(const float* __restrict__ Wk, const float* __restrict__ seed,
                       float* __restrict__ kvec) {
  int l = blockIdx.x;
  const float* Wkl = Wk + (size_t)l * HH2;
  const float* sdl = seed + (size_t)l * HH;
  float* kv = kvec + (size_t)l * HH;
  int w = threadIdx.x >> 6, lane = threadIdx.x & 63;
  float sv[8];
#pragma unroll
  for (int i = 0; i < 8; ++i) sv[i] = sdl[lane * 8 + i];
  for (int row = w; row < HH; row += 8) {
    const float* p = Wkl + (size_t)row * HH + lane * 8;
    float d = 0.f;
#pragma unroll
    for (int i = 0; i < 8; ++i) d += p[i] * sv[i];
#pragma unroll
    for (int o = 32; o > 0; o >>= 1) d += __shfl_xor(d, o);
    if (lane == 0) kv[row] = d;
  }
}

// one pass over x: per-wave online softmax-weighted sum. part[w]: [0]=m,[1]=Z,[2..513]=acc
__global__ void k_pool1(const u16* __restrict__ x, const float* __restrict__ kvec,
                        float* __restrict__ part) {
  int gw = (blockIdx.x * 256 + threadIdx.x) >> 6;
  int lane = threadIdx.x & 63;
  float kl[8];
#pragma unroll
  for (int i = 0; i < 8; ++i) kl[i] = kvec[lane * 8 + i];
  float m = -1e30f, Z = 0.f;
  float acc[8] = {0, 0, 0, 0, 0, 0, 0, 0};
  for (int n = gw; n < NN; n += NPW) {
    u16x8 v = *(const u16x8*)(x + (size_t)n * HH + lane * 8);
    float xl[8], d = 0.f;
#pragma unroll
    for (int i = 0; i < 8; ++i) { xl[i] = b2f(v[i]); d += xl[i] * kl[i]; }
#pragma unroll
    for (int o = 32; o > 0; o >>= 1) d += __shfl_xor(d, o);
    d *= INV_SQRT_H;
    float mn = fmaxf(m, d);
    float c = __expf(m - mn), w = __expf(d - mn);
    Z = Z * c + w;
#pragma unroll
    for (int i = 0; i < 8; ++i) acc[i] = acc[i] * c + w * xl[i];
    m = mn;
  }
  float* p = part + (size_t)gw * 514;
#pragma unroll
  for (int i = 0; i < 8; ++i) p[2 + lane * 8 + i] = acc[i];
  if (lane == 0) { p[0] = m; p[1] = Z; }
}

// combine partials -> gv, then gterm = (gv @ Wv) @ Wg   (512 threads)
__global__ void k_pool2g(const float* __restrict__ part, const float* __restrict__ Wv,
                         const float* __restrict__ Wg, float* __restrict__ gterm) {
  __shared__ float red[512];
  __shared__ float gv[HH];
  __shared__ float g[HH];
  int t = threadIdx.x;
  red[t] = part[(size_t)t * 514];
  __syncthreads();
  for (int s = 256; s > 0; s >>= 1) {
    if (t < s) red[t] = fmaxf(red[t], red[t + s]);
    __syncthreads();
  }
  float M = red[0];
  float s = 0.f, z = 0.f;
  for (int w = 0; w < NPW; ++w) {
    const float* p = part + (size_t)w * 514;
    float e = __expf(p[0] - M);
    z += e * p[1];
    s += e * p[2 + t];
  }
  gv[t] = s / z;
  __syncthreads();
  float a = 0.f;
  for (int i = 0; i < HH; ++i) a += gv[i] * Wv[(size_t)i * HH + t];
  g[t] = a;
  __syncthreads();
  float b = 0.f;
  for (int i = 0; i < HH; ++i) b += g[i] * Wg[(size_t)i * HH + t];
  gterm[t] = b;
}

// ---------------- SpMM: agg_r = (A_r @ x + P_r @ Wpos_r) * invc_r ----------------
__global__ void k_spmm(const int* __restrict__ offs, const int* __restrict__ csr,
                       const float* __restrict__ invc, const float* __restrict__ P,
                       const float* __restrict__ wposL, const u16* __restrict__ x,
                       u16* __restrict__ agg) {
  int r = blockIdx.y;
  int wv = (blockIdx.x * 256 + threadIdx.x) >> 6;
  if (wv >= NN) return;
  int lane = threadIdx.x & 63;
  const int* o = offs + r * (NN + 1);
  const int* cs = csr + (size_t)r * EE;
  const float* wpos = wposL + (size_t)r * 2 * HH;
  int beg = o[wv], end = o[wv + 1];
  float acc[8] = {0, 0, 0, 0, 0, 0, 0, 0};
  int k = beg;
  for (; k + 1 < end; k += 2) {        // 2 gathers in flight
    int s0 = cs[k], s1 = cs[k + 1];
    u16x8 v0 = *(const u16x8*)(x + (size_t)s0 * HH + lane * 8);
    u16x8 v1 = *(const u16x8*)(x + (size_t)s1 * HH + lane * 8);
#pragma unroll
    for (int i = 0; i < 8; ++i) acc[i] += b2f(v0[i]) + b2f(v1[i]);
  }
  if (k < end) {
    int s0 = cs[k];
    u16x8 v0 = *(const u16x8*)(x + (size_t)s0 * HH + lane * 8);
#pragma unroll
    for (int i = 0; i < 8; ++i) acc[i] += b2f(v0[i]);
  }
  float px = P[(size_t)r * NN * 2 + 2 * wv], py = P[(size_t)r * NN * 2 + 2 * wv + 1];
  float ic = invc[(size_t)r * NN + wv];
  u16x8 out;
#pragma unroll
  for (int i = 0; i < 8; ++i) {
    float w0 = wpos[lane * 8 + i];
    float w1 = wpos[HH + lane * 8 + i];
    float v = (acc[i] + px * w0 + py * w1) * ic;
    out[i] = f2b(v);
  }
  __builtin_nontemporal_store(out, (u16x8*)(agg + ((size_t)r * MP + wv) * HH + lane * 8));
}

// ---------------- GEMM: 128x128 tile, 4 waves, XCD-swizzled 1D grid ----------------
// A: [MP][512] bf16 row-major (4 sources by kb). B: B^T [n][k] bf16, row stride 512.
// mode 0: outB = bf16(leaky(C*alpha + gvec[col]))   mode 1: outF = C + bias (bounds-checked)
__global__ __launch_bounds__(256) void k_gemm(
    const u16* __restrict__ A0, const u16* __restrict__ A1,
    const u16* __restrict__ A2, const u16* __restrict__ A3,
    const u16* __restrict__ B0, const u16* __restrict__ B1,
    const u16* __restrict__ B2, const u16* __restrict__ B3,
    int nkt, int mode, float alpha, const float* __restrict__ gvec,
    u16* __restrict__ outB, float* __restrict__ outF,
    const float* __restrict__ bias, int M, int Nout, int G, int gx)
{
  __shared__ u16 lsA[128 * 64];
  __shared__ u16 lsB[128 * 64];
  const int tid = threadIdx.x;
  const int wave = tid >> 6, lane = tid & 63;
  const int wm = (wave >> 1) * 64, wn = (wave & 1) * 64;

  // bijective XCD swizzle (m204): consecutive tl on same XCD; col-fastest order
  const int gid = blockIdx.x;
  const int q = G >> 3, rr = G & 7;
  const int xk = gid & 7, idx = gid >> 3;
  const int tl = xk * q + (xk < rr ? xk : rr) + idx;
  const int rowM0 = (tl / gx) * 128, colN0 = (tl % gx) * 128;

  f32x4 acc[4][4];
#pragma unroll
  for (int i = 0; i < 4; ++i)
#pragma unroll
    for (int j = 0; j < 4; ++j) acc[i][j] = (f32x4){0.f, 0.f, 0.f, 0.f};

  const int rowT = wave * 8 + (lane >> 3);
  const int c8 = lane & 7;
  // hoisted kt-invariant LDS read offsets (u16 units)
  int aoff[2][4], boff[2][4];
#pragma unroll
  for (int K0 = 0; K0 < 2; ++K0)
#pragma unroll
    for (int f = 0; f < 4; ++f) {
      const int cb = K0 * 4 + (lane >> 4);
      const int mm = wm + f * 16 + (lane & 15);
      const int nn = wn + f * 16 + (lane & 15);
      aoff[K0][f] = mm * 64 + ((cb ^ (mm & 7)) << 3);
      boff[K0][f] = nn * 64 + ((cb ^ (nn & 7)) << 3);
    }

  const int nkb = nkt >> 3;
  for (int kb = 0; kb < nkb; ++kb) {
    const u16* As = kb == 0 ? A0 : (kb == 1 ? A1 : (kb == 2 ? A2 : A3));
    const u16* Bs = kb == 0 ? B0 : (kb == 1 ? B1 : (kb == 2 ? B2 : B3));
    for (int k8 = 0; k8 < 8; ++k8) {
      const int koff = k8 * 64;
#pragma unroll
      for (int i = 0; i < 4; ++i) {
        const int r = i * 32 + rowT;
        const int scol = (c8 ^ (r & 7)) * 8;   // inverse-swizzled global source
        async16(As + (size_t)(rowM0 + r) * HH + koff + scol, &lsA[i * 2048 + wave * 512]);
        async16(Bs + (size_t)(colN0 + r) * HH + koff + scol, &lsB[i * 2048 + wave * 512]);
      }
      __syncthreads();
#pragma unroll
      for (int K0 = 0; K0 < 2; ++K0) {
        s16x8 af[4], bfr[4];
#pragma unroll
        for (int f = 0; f < 4; ++f) {
          af[f] = *(const s16x8*)&lsA[aoff[K0][f]];
          bfr[f] = *(const s16x8*)&lsB[boff[K0][f]];
        }
#pragma unroll
        for (int fm = 0; fm < 4; ++fm)
#pragma unroll
          for (int fn = 0; fn < 4; ++fn)
            acc[fm][fn] = __builtin_amdgcn_mfma_f32_16x16x32_bf16(af[fm], bfr[fn], acc[fm][fn], 0, 0, 0);
      }
      __syncthreads();
    }
  }

#pragma unroll
  for (int fm = 0; fm < 4; ++fm) {
#pragma unroll
    for (int fn = 0; fn < 4; ++fn) {
#pragma unroll
      for (int r = 0; r < 4; ++r) {
        const int row = rowM0 + wm + fm * 16 + ((lane >> 4) << 2) + r;  // m89 C/D layout
        const int col = colN0 + wn + fn * 16 + (lane & 15);
        float v = acc[fm][fn][r];
        if (mode == 0) {
          v = v * alpha + (gvec ? gvec[col] : 0.f);
          __builtin_nontemporal_store(f2b(leakyf(v)), &outB[(size_t)row * HH + col]);
        } else {
          if (row < M && col < Nout)
            __builtin_nontemporal_store(v + (bias ? bias[col] : 0.f), &outF[(size_t)row * Nout + col]);
        }
      }
    }
  }
}

// ---------------- host ----------------
extern "C" void kernel_launch(void* const* d_in, const int* in_sizes, int n_in,
                              void* d_out, int out_size, void* d_ws, size_t ws_size,
                              hipStream_t stream) {
  (void)in_sizes; (void)n_in; (void)out_size;
  const float* x_window = (const float*)d_in[0];
  const float* x_pos    = (const float*)d_in[1];
  const int*   e0 = (const int*)d_in[2];
  const int*   e1 = (const int*)d_in[3];
  const int*   e2 = (const int*)d_in[4];
  const float* W_pre  = (const float*)d_in[5];
  const float* W_post = (const float*)d_in[6];
  const float* Wl   = (const float*)d_in[7];
  const float* Wr   = (const float*)d_in[8];
  const float* Wpos = (const float*)d_in[9];
  const float* Wg   = (const float*)d_in[10];
  const float* seed = (const float*)d_in[11];
  const float* Wk   = (const float*)d_in[12];
  const float* Wv   = (const float*)d_in[13];
  const float* W_out= (const float*)d_in[14];
  const float* b_out= (const float*)d_in[15];
  float* out = (float*)d_out;

  char* base = (char*)d_ws;
  size_t off = 0;
  auto alloc = [&](size_t bytes) -> char* {
    char* p = base + off;
    off += (bytes + 255) & ~(size_t)255;
    return p;
  };
  u16* x_a   = (u16*)alloc((size_t)MP * HH * 2);
  u16* x_b   = (u16*)alloc((size_t)MP * HH * 2);
  u16* agg0  = (u16*)alloc((size_t)MP * HH * 2);
  u16* agg1  = (u16*)alloc((size_t)MP * HH * 2);
  u16* agg2  = (u16*)alloc((size_t)MP * HH * 2);
  u16* wlT   = (u16*)alloc((size_t)12 * HH2 * 2);
  u16* wrsT  = (u16*)alloc((size_t)4 * HH2 * 2);
  u16* wpreT = (u16*)alloc((size_t)HH2 * 2);
  u16* wpostT= (u16*)alloc((size_t)HH2 * 2);
  u16* woutT = (u16*)alloc((size_t)256 * HH * 2);
  int* offs  = (int*)alloc((size_t)3 * (NN + 1) * 4);
  int* curs  = (int*)alloc((size_t)3 * NN * 4);    // dead after CSR build -> part overlay
  int* cnt   = (int*)alloc((size_t)3 * NN * 4);    // dead after scan
  int* csr   = (int*)alloc((size_t)3 * EE * 4);
  float* invc = (float*)alloc((size_t)3 * NN * 4);
  float* P    = (float*)alloc((size_t)3 * NN * 2 * 4);
  float* kvec  = (float*)alloc((size_t)LL * HH * 4);
  float* gterm = (float*)alloc(HH * 4);
  int* bsum  = (int*)alloc((size_t)3 * NBLK * 4);
  float* part  = (float*)curs;   // NPW*514*4 = 1.05 MB fits in curs+cnt (1.2 MB)
  if (off > ws_size) return;

  hipMemsetAsync(cnt, 0, (size_t)3 * NN * 4, stream);
  hipMemsetAsync(P, 0, (size_t)3 * NN * 2 * 4, stream);

  k_hist<<<dim3((EE + 255) / 256, 3), 256, 0, stream>>>(e0, e1, e2, cnt);
  k_scan1<<<dim3(NBLK, 3), 1024, 0, stream>>>(cnt, offs, invc, bsum);
  k_scan2<<<1, 256, 0, stream>>>(bsum);
  k_scan3<<<dim3(NBLK, 3), 1024, 0, stream>>>(bsum, offs, curs);
  k_fill<<<dim3((EE + 255) / 256, 3), 256, 0, stream>>>(e0, e1, e2, (const float2*)x_pos,
                                                        curs, csr, P);

  k_transpose_many<<<12 * HH2 / 256, 256, 0, stream>>>(Wl, wlT, 12);
  k_sum3_all<<<4 * HH2 / 256, 256, 0, stream>>>(Wr, wrsT);
  k_transpose_many<<<HH2 / 256, 256, 0, stream>>>(W_pre, wpreT, 1);
  k_transpose_many<<<HH2 / 256, 256, 0, stream>>>(W_post, wpostT, 1);
  k_transpose_pad<<<(HH * 256) / 256, 256, 0, stream>>>(W_out, woutT, HH, OUTC, 256);
  k_kvec<<<LL, 512, 0, stream>>>(Wk, seed, kvec);

  k_cvt<<<(NN * HH / 8 + 255) / 256, 256, 0, stream>>>(x_window, x_b, NN * HH / 8);
  k_zero_pads<<<((MP - NN) * HH * 5 + 255) / 256, 256, 0, stream>>>(x_a, x_b, agg0, agg1, agg2);

  const u16* nul = nullptr;
  const int G4 = 4 * (MP / 128), G2 = 2 * (MP / 128);
  // pretransform: t = leaky(xw @ W_pre) -> agg0 ; x0 = leaky(t @ W_post) -> x_a
  k_gemm<<<G4, 256, 0, stream>>>(x_b, nul, nul, nul, wpreT, nul, nul, nul,
                                 8, 0, 1.f, nullptr, agg0, nullptr, nullptr, NN, HH, G4, 4);
  k_gemm<<<G4, 256, 0, stream>>>(agg0, nul, nul, nul, wpostT, nul, nul, nul,
                                 8, 0, 1.f, nullptr, x_a, nullptr, nullptr, NN, HH, G4, 4);

  u16* cur = x_a; u16* nxt = x_b;
  for (int l = 0; l < LL; ++l) {
    k_pool1<<<NPW / 4, 256, 0, stream>>>(cur, kvec + (size_t)l * HH, part);
    k_pool2g<<<1, 512, 0, stream>>>(part, Wv + (size_t)l * HH2, Wg + (size_t)l * HH2, gterm);
    k_spmm<<<dim3(NN / 4, 3), 256, 0, stream>>>(offs, csr, invc, P,
                                                Wpos + (size_t)l * 3 * 2 * HH, cur, agg0);
    k_gemm<<<G4, 256, 0, stream>>>(
        agg0, agg1, agg2, cur,
        wlT + (size_t)(l * 3 + 0) * HH2, wlT + (size_t)(l * 3 + 1) * HH2,
        wlT + (size_t)(l * 3 + 2) * HH2, wrsT + (size_t)l * HH2,
        32, 0, (1.f / 3.f), gterm, nxt, nullptr, nullptr, NN, HH, G4, 4);
    u16* t = cur; cur = nxt; nxt = t;
  }
  // final projection: out = x @ W_out + b_out
  k_gemm<<<G2, 256, 0, stream>>>(cur, nul, nul, nul, woutT, nul, nul, nul,
                                 8, 1, 1.f, nullptr, nullptr, out, b_out, NN, OUTC, G2, 2);
}